// Round 13
// baseline (106.936 us; speedup 1.0000x reference)
//
#include <hip/hip_runtime.h>

typedef short bf16x8 __attribute__((ext_vector_type(8)));
typedef float f32x16 __attribute__((ext_vector_type(16)));

#define BIG_F 1e10f
constexpr int B = 16;
constexpr int N = 4096;
constexpr int ROWS = 256;        // rows (x-points) per block
constexpr int COLS = 512;        // cols (y-points) per block
constexpr int NRB = N / ROWS;    // 16
constexpr int NCB = N / COLS;    // 8
constexpr int NCC = COLS / 32;   // 16 col chunks of 32
constexpr int PST = 20;          // pack stride in shorts (10 dwords: max 2-way bank alias)

// truncating bf16 hi/lo split: v ~= hi + lo with |v-hi-lo| <= 2^-16 |v|
__device__ __forceinline__ void split(float v, unsigned short& h, unsigned short& l) {
    unsigned hb = __float_as_uint(v) & 0xFFFF0000u;
    h = (unsigned short)(hb >> 16);
    float r = v - __uint_as_float(hb);
    l = (unsigned short)(__float_as_uint(r) >> 16);
}

__device__ __forceinline__ float min3f(float a, float b, float c) {
    return fminf(fminf(a, b), c);
}

// P[n,m] = xx[n] + yy[m] - 2 x_n . y_m (+BIG on masked rows/cols) via
// mfma_f32_32x32x16_bf16 (K=16 fully used, no zero pad).
// K-vectors (exactness verified R9 at absmax 0.0):
//   A_k(n) = [ah0..2, ah0..2, al0..2, al0..2, xxh, xxl, 1, 1]
//   B_k(m) = [yh0..2, yl0..2, yh0..2, yl0..2, 1, 1, yyh, yyl]
// Operand layouts (32x32x16): A: lane L holds A[m=L&31][k=(L>>5)*8+j];
// B: lane L holds B[k=(L>>5)*8+j][n=L&31];
// C/D (m74/m101-verified): col=L&31, row=(reg&3)+8*(reg>>2)+4*(L>>5).
__global__ __launch_bounds__(256) void chamfer_mfma(
    const float* __restrict__ x, const float* __restrict__ y,
    const int* __restrict__ mask,
    float* __restrict__ rowpart,   // [B][NCB][N] exclusive slots (no init)
    float* __restrict__ colpart,   // [B][NRB][N]
    float* __restrict__ out)
{
    const int rb = blockIdx.x & 15;   // row-block
    const int cb = blockIdx.x >> 4;   // col-block
    const int b  = blockIdx.y;
    const int t  = threadIdx.x;

    __shared__ unsigned short Apack[ROWS * PST];  // 10 KB
    __shared__ unsigned short Bpack[COLS * PST];  // 20 KB
    __shared__ float colbuf[4][COLS];             // 8 KB

    if (blockIdx.x == 0 && b == 0 && t == 0) out[0] = 0.0f;  // finalize = next dispatch

    const unsigned short one = 0x3F80;  // bf16 1.0

    // ---- pack A: 256 x-points, one per thread ----
    {
        int n = rb * ROWS + t;
        const float* xb = x + (size_t)b * 3 * N;
        float x0 = xb[n], x1 = xb[N + n], x2 = xb[2 * N + n];
        float madd = mask[b * N + n] ? 0.0f : BIG_F;
        float xx = fmaf(x2, x2, fmaf(x1, x1, x0 * x0)) + madd;
        unsigned short ah0, al0, ah1, al1, ah2, al2, xh, xl;
        split(-2.0f * x0, ah0, al0);
        split(-2.0f * x1, ah1, al1);
        split(-2.0f * x2, ah2, al2);
        split(xx, xh, xl);
        unsigned short* p = &Apack[t * PST];
        p[0] = ah0; p[1] = ah1; p[2] = ah2; p[3] = ah0; p[4] = ah1; p[5] = ah2;
        p[6] = al0; p[7] = al1; p[8] = al2; p[9] = al0; p[10] = al1; p[11] = al2;
        p[12] = xh; p[13] = xl; p[14] = one; p[15] = one;
    }
    // ---- pack B: 512 y-points, two per thread ----
#pragma unroll
    for (int i = 0; i < 2; ++i) {
        int c = t + i * 256;
        int m = cb * COLS + c;
        const float* yb = y + (size_t)b * 3 * N;
        float y0 = yb[m], y1 = yb[N + m], y2 = yb[2 * N + m];
        float madd = mask[b * N + m] ? 0.0f : BIG_F;
        float yy = fmaf(y2, y2, fmaf(y1, y1, y0 * y0)) + madd;
        unsigned short yh0, yl0, yh1, yl1, yh2, yl2, qh, ql;
        split(y0, yh0, yl0);
        split(y1, yh1, yl1);
        split(y2, yh2, yl2);
        split(yy, qh, ql);
        unsigned short* p = &Bpack[c * PST];
        p[0] = yh0; p[1] = yh1; p[2] = yh2; p[3] = yl0; p[4] = yl1; p[5] = yl2;
        p[6] = yh0; p[7] = yh1; p[8] = yh2; p[9] = yl0; p[10] = yl1; p[11] = yl2;
        p[12] = one; p[13] = one; p[14] = qh; p[15] = ql;
    }
    __syncthreads();

    const int w  = t >> 6;    // wave 0..3 (owns rows w*64..w*64+63)
    const int L  = t & 63;
    const int h  = L >> 5;    // k-half 0..1
    const int ln = L & 31;

    // A-frags: 2 row-subtiles of 32 rows each
    bf16x8 afr[2];
#pragma unroll
    for (int s = 0; s < 2; ++s)
        afr[s] = *(const bf16x8*)&Apack[(w * 64 + s * 32 + ln) * PST + h * 8];

    float rm[2][16];
#pragma unroll
    for (int s = 0; s < 2; ++s)
#pragma unroll
        for (int i = 0; i < 16; ++i) rm[s][i] = 1e30f;

    // 1-deep B-frag prefetch
    bf16x8 nbf = *(const bf16x8*)&Bpack[ln * PST + h * 8];

    for (int cc = 0; cc < NCC; ++cc) {
        bf16x8 bf = nbf;
        if (cc + 1 < NCC)
            nbf = *(const bf16x8*)&Bpack[((cc + 1) * 32 + ln) * PST + h * 8];

        f32x16 C0, C1;
        {
            f32x16 z = {};
            C0 = __builtin_amdgcn_mfma_f32_32x32x16_bf16(afr[0], bf, z, 0, 0, 0);
            C1 = __builtin_amdgcn_mfma_f32_32x32x16_bf16(afr[1], bf, z, 0, 0, 0);
        }
        // row-min accumulate: reg i of subtile s is row s*32+(i&3)+8*(i>>2)+4*h,
        // col cc*32+ln — one fmin per reg
#pragma unroll
        for (int i = 0; i < 16; ++i) {
            rm[0][i] = fminf(rm[0][i], C0[i]);
            rm[1][i] = fminf(rm[1][i], C1[i]);
        }
        // col-min: all 32 regs share col ln -> in-lane tree (covers this lane's
        // 32 of the wave's 64 rows), then one xor-32 to merge the other half
        float v = fminf(fminf(min3f(C0[0], C0[1], C0[2]),
                              min3f(C0[3], C0[4], C0[5])),
                        fminf(min3f(C0[6], C0[7], C0[8]),
                              min3f(C0[9], C0[10], C0[11])));
        v = fminf(v, fminf(fminf(C0[12], C0[13]), fminf(C0[14], C0[15])));
        float v1 = fminf(fminf(min3f(C1[0], C1[1], C1[2]),
                               min3f(C1[3], C1[4], C1[5])),
                         fminf(min3f(C1[6], C1[7], C1[8]),
                               min3f(C1[9], C1[10], C1[11])));
        v1 = fminf(v1, fminf(fminf(C1[12], C1[13]), fminf(C1[14], C1[15])));
        v = fminf(v, v1);
        v = fminf(v, __shfl_xor(v, 32));
        if (h == 0) colbuf[w][cc * 32 + ln] = v;
    }

    // finish row-mins: reduce across the 32 lanes (within each k-half)
#pragma unroll
    for (int off = 1; off <= 16; off <<= 1)
#pragma unroll
        for (int s = 0; s < 2; ++s)
#pragma unroll
            for (int i = 0; i < 16; ++i)
                rm[s][i] = fminf(rm[s][i], __shfl_xor(rm[s][i], off));
    if (ln == 0) {
        float* rp = rowpart + ((size_t)b * NCB + cb) * N + rb * ROWS + w * 64;
#pragma unroll
        for (int s = 0; s < 2; ++s)
#pragma unroll
            for (int i = 0; i < 16; ++i)
                rp[s * 32 + (i & 3) + 8 * (i >> 2) + 4 * h] = rm[s][i];
    }

    __syncthreads();
    // combine 4 waves' col-mins -> block's col partial (min over 256 rows)
    for (int c = t; c < COLS; c += 256) {
        float v = fminf(fminf(colbuf[0][c], colbuf[1][c]),
                        fminf(colbuf[2][c], colbuf[3][c]));
        colpart[((size_t)b * NRB + rb) * N + cb * COLS + c] = v;
    }
}

__global__ __launch_bounds__(256) void finalize_kernel(
    const int* __restrict__ mask,
    const float* __restrict__ rowpart, const float* __restrict__ colpart,
    float* __restrict__ out)
{
    const int b   = blockIdx.x & 15;
    const int dir = (blockIdx.x >> 4) & 1;
    const int q   = blockIdx.x >> 5;   // quarter 0..3
    const int t   = threadIdx.x;
    const int* mrow = mask + b * N;

    int cnt = 0;
    for (int i = t; i < N / 4; i += 256) {
        int4 mk = ((const int4*)mrow)[i];
        cnt += mk.x + mk.y + mk.z + mk.w;
    }

    const float* base = dir ? (colpart + (size_t)b * NRB * N)
                            : (rowpart + (size_t)b * NCB * N);
    const int npb = dir ? NRB : NCB;

    const int p0 = q * 1024 + t * 4;
    float4 mn = *(const float4*)(base + p0);
    for (int pb = 1; pb < npb; ++pb) {
        float4 v = *(const float4*)(base + (size_t)pb * N + p0);
        mn.x = fminf(mn.x, v.x); mn.y = fminf(mn.y, v.y);
        mn.z = fminf(mn.z, v.z); mn.w = fminf(mn.w, v.w);
    }
    int4 mk = *(const int4*)(mrow + p0);
    float s = (mk.x ? mn.x : 0.f) + (mk.y ? mn.y : 0.f)
            + (mk.z ? mn.z : 0.f) + (mk.w ? mn.w : 0.f);

    for (int off = 32; off > 0; off >>= 1) {
        s   += __shfl_down(s, off);
        cnt += __shfl_down(cnt, off);
    }
    __shared__ float rs[4];
    __shared__ int   rc[4];
    const int wv = t >> 6;
    if ((t & 63) == 0) { rs[wv] = s; rc[wv] = cnt; }
    __syncthreads();
    if (t == 0) {
        float S = rs[0] + rs[1] + rs[2] + rs[3];
        float C = (float)(rc[0] + rc[1] + rc[2] + rc[3]);
        atomicAdd(out, (S / C) * (1.0f / 16.0f));
    }
}

extern "C" void kernel_launch(void* const* d_in, const int* in_sizes, int n_in,
                              void* d_out, int out_size, void* d_ws, size_t ws_size,
                              hipStream_t stream) {
    const float* x    = (const float*)d_in[0];
    const float* y    = (const float*)d_in[1];
    const int*   mask = (const int*)d_in[2];

    float* rowpart = (float*)d_ws;                    // B*NCB*N floats = 2 MB
    float* colpart = rowpart + (size_t)B * NCB * N;   // B*NRB*N floats = 4 MB

    chamfer_mfma<<<dim3(NRB * NCB, B), 256, 0, stream>>>(
        x, y, mask, rowpart, colpart, (float*)d_out);
    finalize_kernel<<<dim3(128), 256, 0, stream>>>(
        mask, rowpart, colpart, (float*)d_out);
}